// Round 7
// baseline (525.285 us; speedup 1.0000x reference)
//
#include <hip/hip_runtime.h>

#define Q_LBF 1e-4f
#define DTF   3600.0f
#define NN    131071
#define SENT  0x7FC00001u   // NaN sentinel: computed stream values are always finite
#define W1    2048          // S1 width = level-5 node count
#define W2    32            // S2 width = level-11 node count
#define PRESYNC_ROW 20      // consumer start-lag anchor (producer writes it at step 24)

#if __has_builtin(__builtin_amdgcn_exp2f)
#define FEXP2(x) __builtin_amdgcn_exp2f(x)
#else
#define FEXP2(x) exp2f(x)
#endif
#if __has_builtin(__builtin_amdgcn_logf)
#define FLOG2(x) __builtin_amdgcn_logf(x)
#else
#define FLOG2(x) log2f(x)
#endif
#if __has_builtin(__builtin_amdgcn_rcpf)
#define FRCP(x) __builtin_amdgcn_rcpf(x)
#else
#define FRCP(x) (1.0f/(x))
#endif

#define SBAR() __builtin_amdgcn_sched_barrier(0)

// Async global->LDS, 4B per lane. Dest is WAVE-UNIFORM base (+ lane*4 by HW);
// src is per-lane. No VGPR destination => the register allocator CANNOT
// collapse this prefetch. Tracked by vmcnt.
__device__ __forceinline__ void gload4(const float* g, float* l) {
  __builtin_amdgcn_global_load_lds(
      (const __attribute__((address_space(1))) unsigned*)g,
      (__attribute__((address_space(3))) unsigned*)l, 4, 0, 0);
}

// Per-node time-invariant constants (everything except q folded once).
struct NC { float a1, e, tw, ssd, w2, a2, kd, kx; };

__device__ __forceinline__ NC make_nc(const float* __restrict__ nr,
                                      const float* __restrict__ qsr,
                                      const float* __restrict__ len,
                                      const float* __restrict__ slp,
                                      const float* __restrict__ twp,
                                      const float* __restrict__ ssp,
                                      const float* __restrict__ xsp,
                                      int g) {
  float n  = fmaf(nr[g], 0.34f, 0.01f);
  float qs = 3.0f * qsr[g];
  float s0 = fmaxf(slp[g], 1e-4f);
  float rs = sqrtf(s0);
  float L  = len[g];
  float x  = xsp[g];
  float ss = ssp[g];
  NC c;
  c.a1  = n * (qs + 1.0f) / fmaf(21.0f, rs, 1e-8f);
  c.e   = 3.0f / fmaf(3.0f, qs, 5.0f);
  c.tw  = twp[g];
  c.ssd = 2.0f * ss;
  c.w2  = 2.0f * sqrtf(fmaf(ss, ss, 1.0f));
  c.a2  = rs / n;
  float kl = 1.2f * L;
  c.kd  = kl * (1.0f - x);
  c.kx  = kl * x;
  return c;
}

__device__ __forceinline__ float node_b(const NC& c, float q, float qpc, float it,
                                        float& c1o) {
  float z    = q * c.a1;
  float d    = fmaxf(FEXP2(c.e * FLOG2(z)), 0.01f);
  float bot  = fmaxf(fmaf(-c.ssd, d, c.tw), 0.1f);
  float area = (c.tw + bot) * (0.5f * d);
  float wet  = fmaf(c.w2, d, bot);
  float R    = area * FRCP(wet);
  float v2   = c.a2 * FEXP2(0.66666668f * FLOG2(R));
  v2 = fminf(fmaxf(v2, 0.3f), 15.0f);
  float rv   = FRCP(v2);
  float rden = FRCP(fmaf(c.kd, rv, DTF));
  float c2   = fmaf(c.kx, rv, DTF) * rden;
  float c4   = 7200.0f * rden;
  c1o = c4 - c2;
  float c3 = 1.0f - c4;
  return fmaf(c2, it, fmaf(c3, q, c4 * qpc));
}

__device__ __forceinline__ int iclamp(int v, int lo, int hi) {
  return v < lo ? lo : (v > hi ? hi : v);
}

// Fence-free cross-XCD streaming via relaxed agent-scope atomics.
// One writer per word; 32-bit words can't tear; sentinel = "not written yet".
__device__ __forceinline__ void st_stream(float* p, float v) {
  __hip_atomic_store((unsigned*)p, __float_as_uint(v),
                     __ATOMIC_RELAXED, __HIP_MEMORY_SCOPE_AGENT);
}
__device__ __forceinline__ uint2 ld2_relaxed(const float* p) {
  const unsigned* u = (const unsigned*)p;
  uint2 r;
  r.x = __hip_atomic_load(u,     __ATOMIC_RELAXED, __HIP_MEMORY_SCOPE_AGENT);
  r.y = __hip_atomic_load(u + 1, __ATOMIC_RELAXED, __HIP_MEMORY_SCOPE_AGENT);
  return r;
}
__device__ __forceinline__ uint2 ld2_block(const float* p) {
  uint2 r = ld2_relaxed(p);
  while (r.x == SENT || r.y == SENT) {
    __builtin_amdgcn_s_sleep(1);
    r = ld2_relaxed(p);
  }
  return r;
}

// ---- role A: levels 0..5, depth-6 subtree per wave (2048 waves).
// LDS ring: 8 slots x 64 floats (qp row s-e per lane). Per step vm ops are
// STATIC: [1 st_stream ; 1 gload4]. Exact wait bound: gload(slot s+1) has 12
// younger vm ops at the step-s wait => vmcnt(<=11) guarantees it; use 10.
__device__ __forceinline__ void run_A(
    const float* __restrict__ qp,
    const float* __restrict__ nr, const float* __restrict__ qsr,
    const float* __restrict__ len, const float* __restrict__ slp,
    const float* __restrict__ twp, const float* __restrict__ ssp,
    const float* __restrict__ xsp,
    float* __restrict__ S1, float* __restrict__ D1,
    float* lds, int w, int lane) {
  int e, g, cs0;
  const bool leaf = lane < 32;
  if (leaf)           { e = 0; g = (w << 5) + lane;               cs0 = 0; }
  else if (lane < 48) { e = 1; g = 65536  + (w << 4) + (lane-32); cs0 = 2*(lane-32); }
  else if (lane < 56) { e = 2; g = 98304  + (w << 3) + (lane-48); cs0 = 32 + 2*(lane-48); }
  else if (lane < 60) { e = 3; g = 114688 + (w << 2) + (lane-56); cs0 = 48 + 2*(lane-56); }
  else if (lane < 62) { e = 4; g = 122880 + (w << 1) + (lane-60); cs0 = 56 + 2*(lane-60); }
  else                { e = 5; g = 126976 + w;                    cs0 = 60; }
  NC c = make_nc(nr,qsr,len,slp,twp,ssp,xsp, g);
  float q0 = qp[g];
  float i0 = __shfl(q0, cs0), i1 = __shfl(q0, cs0 + 1);
  const float itInit = i0 + i1;              // children's raw q_prime[0] (t=0 i_t)
  if (lane == 62) st_stream(&S1[w], q0);     // row 0 = raw q_prime[0] of L5 root
  float* dumpP = D1 + w;
  const int offMax = 335 * NN + g;
  // prologue: [dummy store ; gload] x8 — matches the steady per-step op group
#pragma unroll
  for (int j = 0; j < 8; ++j) {
    st_stream(dumpP, 0.0f);
    gload4(qp + iclamp(j - e, 0, 335) * NN + g, lds + j * 64);
    SBAR();
  }
  int off = (8 - e) * NN + g;
  asm volatile("s_waitcnt vmcnt(0)" ::: "memory"); SBAR();
  float Q = lds[lane];                       // row -e..0 clamped = row 0's value
  float qc = q0, ul = q0, pu0 = 0.0f, pu1 = 0.0f;
  for (int so = 0; so < 344; so += 8) {
#pragma unroll
    for (int j = 0; j < 8; ++j) {
      const int s = so + j;
      asm volatile("s_waitcnt vmcnt(10)" ::: "memory"); SBAR();
      float Qn = lds[((j + 1) & 7) * 64 + lane];  // row s+1-e, read 1 step early
      float u0 = __shfl(ul, cs0), u1 = __shfl(ul, cs0 + 1);
      float itg = (s == e) ? itInit : (fmaxf(pu0, Q_LBF) + fmaxf(pu1, Q_LBF));
      if (s == e) qc = q0;                   // epoch start: raw q_prime[0]
      float it  = leaf ? 0.0f : itg;
      float chn = leaf ? 0.0f : (u0 + u1);
      float qpc = fmaxf(Q, Q_LBF);
      float c1;
      float b  = node_b(c, qc, qpc, it, c1);
      float un = fmaf(c1, chn, b);
      qc = fmaxf(un, Q_LBF); ul = un;
      pu0 = u0; pu1 = u1;
      // unconditional store (static vm count): non-root / out-of-range -> dump
      float* dst = (lane == 62 && s >= 5 && s <= 339) ? (S1 + (s - 4) * W1 + w)
                                                      : dumpP;
      st_stream(dst, un);
      gload4(qp + off, lds + j * 64);        // row s+8-e -> slot s%8 (freed)
      off = min(off + NN, offMax);
      Q = Qn;
    }
  }
}

// ---- role B: levels 6..11, 32 waves. LDS ring: 8 slots x (S1.x | S1.y | qp),
// 192 floats/slot. Per step vm ops STATIC: [store ; gx ; gy ; gq]. Exact wait
// bound for slot s+2's gy: 20-23 younger ops => vmcnt(18). fo/fn held in regs
// (read 1-2 steps ahead); sentinel fallback corrects regs, rotation propagates.
__device__ __forceinline__ void run_B(
    const float* __restrict__ qp,
    const float* __restrict__ nr, const float* __restrict__ qsr,
    const float* __restrict__ len, const float* __restrict__ slp,
    const float* __restrict__ twp, const float* __restrict__ ssp,
    const float* __restrict__ xsp,
    const float* __restrict__ S1, float* __restrict__ S2,
    float* __restrict__ D2, float* lds, int r, int lane) {
  int e, g, cs0;
  const bool leaf = lane < 32;
  const int jl = leaf ? lane : 31;
  if (leaf)           { e = 0; g = 129024 + (r << 5) + lane;      cs0 = 0; }
  else if (lane < 48) { e = 1; g = 130048 + (r << 4) + (lane-32); cs0 = 2*(lane-32); }
  else if (lane < 56) { e = 2; g = 130560 + (r << 3) + (lane-48); cs0 = 32 + 2*(lane-48); }
  else if (lane < 60) { e = 3; g = 130816 + (r << 2) + (lane-56); cs0 = 48 + 2*(lane-56); }
  else if (lane < 62) { e = 4; g = 130944 + (r << 1) + (lane-60); cs0 = 56 + 2*(lane-60); }
  else                { e = 5; g = 131008 + r;                    cs0 = 60; }
  const int col2 = ((r << 5) + jl) * 2;      // child pair columns in S1 rows
  NC c = make_nc(nr,qsr,len,slp,twp,ssp,xsp, g);
  float q0 = qp[g];
  float i0 = __shfl(q0, cs0), i1 = __shfl(q0, cs0 + 1);
  const float itInit = i0 + i1;
  if (lane == 62) st_stream(&S2[r], q0);
  // one-time start-lag sync: producer >= 24 steps in before we begin
  {
    uint2 t0 = ld2_block(S1 + PRESYNC_ROW * W1 + col2);
    asm volatile("" :: "v"(t0.x), "v"(t0.y));
  }
  SBAR();
  float* dumpP = D2 + r;
  const int offMax  = 335 * NN + g;
  const int soffMax = 335 * W1 + col2;
#pragma unroll
  for (int j = 0; j < 8; ++j) {
    st_stream(dumpP, 0.0f);
    gload4(S1 + j * W1 + col2,     lds + j * 192);
    gload4(S1 + j * W1 + col2 + 1, lds + j * 192 + 64);
    gload4(qp + iclamp(j - e, 0, 335) * NN + g, lds + j * 192 + 128);
    SBAR();
  }
  int soff = 8 * W1 + col2;
  int off  = (8 - e) * NN + g;
  asm volatile("s_waitcnt vmcnt(0)" ::: "memory"); SBAR();
  float r0x = lds[lane],       r0y = lds[64 + lane];        // S1 row 0
  float r1x = lds[192 + lane], r1y = lds[192 + 64 + lane];  // S1 row 1
  float Q   = lds[128 + lane];                              // qp row 0
  float qc = q0, ul = q0, pu0 = 0.0f, pu1 = 0.0f;
  __builtin_amdgcn_s_setprio(2);             // pace A instead of queueing behind it
  for (int so = 0; so < 344; so += 8) {
#pragma unroll
    for (int j = 0; j < 8; ++j) {
      const int s = so + j;
      asm volatile("s_waitcnt vmcnt(18)" ::: "memory"); SBAR();
      float n2x = lds[((j + 2) & 7) * 192 + lane];        // S1 row s+2
      float n2y = lds[((j + 2) & 7) * 192 + 64 + lane];
      float Qn  = lds[((j + 1) & 7) * 192 + 128 + lane];  // qp row s+1-e
      if (__builtin_expect((__float_as_uint(r0x) == SENT) |
                           (__float_as_uint(r0y) == SENT) |
                           (__float_as_uint(r1x) == SENT) |
                           (__float_as_uint(r1y) == SENT), 0)) {
        __builtin_amdgcn_s_setprio(0);
        uint2 fo = ld2_block(S1 + iclamp(s,     0, 335) * W1 + col2);
        uint2 fn = ld2_block(S1 + iclamp(s + 1, 0, 335) * W1 + col2);
        __builtin_amdgcn_s_setprio(2);
        r0x = __uint_as_float(fo.x); r0y = __uint_as_float(fo.y);
        r1x = __uint_as_float(fn.x); r1y = __uint_as_float(fn.y);
      }
      float u0 = __shfl(ul, cs0), u1 = __shfl(ul, cs0 + 1);
      float itg = (s == e) ? itInit : (fmaxf(pu0, Q_LBF) + fmaxf(pu1, Q_LBF));
      if (s == e) qc = q0;
      float it  = leaf ? (fmaxf(r0x, Q_LBF) + fmaxf(r0y, Q_LBF)) : itg;
      float chn = leaf ? (r1x + r1y) : (u0 + u1);
      float qpc = fmaxf(Q, Q_LBF);
      float c1;
      float b  = node_b(c, qc, qpc, it, c1);
      float un = fmaf(c1, chn, b);
      qc = fmaxf(un, Q_LBF); ul = un;
      pu0 = u0; pu1 = u1;
      float* dst = (lane == 62 && s >= 5 && s <= 339) ? (S2 + (s - 4) * W2 + r)
                                                      : dumpP;
      st_stream(dst, un);
      gload4(S1 + soff,     lds + j * 192);
      gload4(S1 + soff + 1, lds + j * 192 + 64);
      gload4(qp + off,      lds + j * 192 + 128);
      soff = min(soff + W1, soffMax);
      off  = min(off + NN, offMax);
      r0x = r1x; r0y = r1y; r1x = n2x; r1y = n2y; Q = Qn;
    }
  }
  __builtin_amdgcn_s_setprio(0);
}

// ---- role C: levels 12..16, one wave; mirrors B against S2, writes out[].
__device__ __forceinline__ void run_C(
    const float* __restrict__ qp,
    const float* __restrict__ nr, const float* __restrict__ qsr,
    const float* __restrict__ len, const float* __restrict__ slp,
    const float* __restrict__ twp, const float* __restrict__ ssp,
    const float* __restrict__ xsp,
    const float* __restrict__ S2, float* __restrict__ D2,
    float* __restrict__ out, float* lds, int lane) {
  int e, g, cs0;
  const bool leaf = lane < 16;
  const int jl = leaf ? lane : 15;
  if (leaf)           { e = 0; g = 131040 + lane;        cs0 = 0; }
  else if (lane < 24) { e = 1; g = 131056 + (lane - 16); cs0 = 2*(lane-16); }
  else if (lane < 28) { e = 2; g = 131064 + (lane - 24); cs0 = 16 + 2*(lane-24); }
  else if (lane < 30) { e = 3; g = 131068 + (lane - 28); cs0 = 24 + 2*(lane-28); }
  else                { e = 4; g = 131070;               cs0 = 28; }
  const int col2 = jl * 2;
  NC c = make_nc(nr,qsr,len,slp,twp,ssp,xsp, g);
  float q0 = qp[g];
  float i0 = __shfl(q0, cs0), i1 = __shfl(q0, cs0 + 1);
  const float itInit = i0 + i1;
  if (lane == 30) out[0] = fmaxf(q0, Q_LBF);
  {
    uint2 t0 = ld2_block(S2 + PRESYNC_ROW * W2 + col2);
    asm volatile("" :: "v"(t0.x), "v"(t0.y));
  }
  SBAR();
  float* dumpP = D2 + 32;
  const int offMax  = 335 * NN + g;
  const int soffMax = 335 * W2 + col2;
#pragma unroll
  for (int j = 0; j < 8; ++j) {
    st_stream(dumpP, 0.0f);
    gload4(S2 + j * W2 + col2,     lds + j * 192);
    gload4(S2 + j * W2 + col2 + 1, lds + j * 192 + 64);
    gload4(qp + iclamp(j - e, 0, 335) * NN + g, lds + j * 192 + 128);
    SBAR();
  }
  int soff = 8 * W2 + col2;
  int off  = (8 - e) * NN + g;
  asm volatile("s_waitcnt vmcnt(0)" ::: "memory"); SBAR();
  float r0x = lds[lane],       r0y = lds[64 + lane];
  float r1x = lds[192 + lane], r1y = lds[192 + 64 + lane];
  float Q   = lds[128 + lane];
  float qc = q0, ul = q0, pu0 = 0.0f, pu1 = 0.0f;
  __builtin_amdgcn_s_setprio(3);
  for (int so = 0; so < 344; so += 8) {
#pragma unroll
    for (int j = 0; j < 8; ++j) {
      const int s = so + j;
      asm volatile("s_waitcnt vmcnt(18)" ::: "memory"); SBAR();
      float n2x = lds[((j + 2) & 7) * 192 + lane];
      float n2y = lds[((j + 2) & 7) * 192 + 64 + lane];
      float Qn  = lds[((j + 1) & 7) * 192 + 128 + lane];
      if (__builtin_expect((__float_as_uint(r0x) == SENT) |
                           (__float_as_uint(r0y) == SENT) |
                           (__float_as_uint(r1x) == SENT) |
                           (__float_as_uint(r1y) == SENT), 0)) {
        __builtin_amdgcn_s_setprio(0);
        uint2 fo = ld2_block(S2 + iclamp(s,     0, 335) * W2 + col2);
        uint2 fn = ld2_block(S2 + iclamp(s + 1, 0, 335) * W2 + col2);
        __builtin_amdgcn_s_setprio(3);
        r0x = __uint_as_float(fo.x); r0y = __uint_as_float(fo.y);
        r1x = __uint_as_float(fn.x); r1y = __uint_as_float(fn.y);
      }
      float u0 = __shfl(ul, cs0), u1 = __shfl(ul, cs0 + 1);
      float itg = (s == e) ? itInit : (fmaxf(pu0, Q_LBF) + fmaxf(pu1, Q_LBF));
      if (s == e) qc = q0;
      float it  = leaf ? (fmaxf(r0x, Q_LBF) + fmaxf(r0y, Q_LBF)) : itg;
      float chn = leaf ? (r1x + r1y) : (u0 + u1);
      float qpc = fmaxf(Q, Q_LBF);
      float c1;
      float b  = node_b(c, qc, qpc, it, c1);
      float un = fmaf(c1, chn, b);
      qc = fmaxf(un, Q_LBF); ul = un;
      pu0 = u0; pu1 = u1;
      // unconditional store (static vm count): non-root / out-of-range -> dump
      float* dst = (lane == 30 && s >= 4 && s <= 338) ? (out + (s - 3)) : dumpP;
      st_stream(dst, fmaxf(un, Q_LBF));
      gload4(S2 + soff,     lds + j * 192);
      gload4(S2 + soff + 1, lds + j * 192 + 64);
      gload4(qp + off,      lds + j * 192 + 128);
      soff = min(soff + W2, soffMax);
      off  = min(off + NN, offMax);
      r0x = r1x; r0y = r1y; r1x = n2x; r1y = n2y; Q = Qn;
    }
  }
  __builtin_amdgcn_s_setprio(0);
}

__global__ __launch_bounds__(256) void kinit(unsigned* __restrict__ F, int n) {
  int i = blockIdx.x * 256 + threadIdx.x;
  int stride = gridDim.x * 256;
  for (; i < n; i += stride) F[i] = SENT;
}

// 256 blocks x 9 waves: waves 0-7 = A (2048 waves), wave 8 = B on blocks 0-31,
// C on block 32. One block per CU, all roles co-resident from t=0.
// LDS: A 8 waves x 8 slots x 256B = 16KB; B/C 8 slots x 768B = 6KB.
__global__ __launch_bounds__(576, 3) void fused(
    const float* __restrict__ qp,
    const float* __restrict__ nr, const float* __restrict__ qsr,
    const float* __restrict__ len, const float* __restrict__ slp,
    const float* __restrict__ twp, const float* __restrict__ ssp,
    const float* __restrict__ xsp,
    float* __restrict__ S1, float* __restrict__ S2,
    float* __restrict__ D1, float* __restrict__ D2,
    float* __restrict__ out) {
  __shared__ float pool[8 * 512 + 8 * 192];
  const int wv = threadIdx.x >> 6;
  const int lane = threadIdx.x & 63;
  const int b = blockIdx.x;
  if (wv < 8) {
    run_A(qp, nr, qsr, len, slp, twp, ssp, xsp, S1, D1,
          pool + wv * 512, (b << 3) + wv, lane);
  } else if (b < 32) {
    run_B(qp, nr, qsr, len, slp, twp, ssp, xsp, S1, S2, D2,
          pool + 4096, b, lane);
  } else if (b == 32) {
    run_C(qp, nr, qsr, len, slp, twp, ssp, xsp, S2, D2, out,
          pool + 4096, lane);
  }
}

extern "C" void kernel_launch(void* const* d_in, const int* in_sizes, int n_in,
                              void* d_out, int out_size, void* d_ws, size_t ws_size,
                              hipStream_t stream) {
  const float* q_prime = (const float*)d_in[0];
  const float* n_raw   = (const float*)d_in[1];
  const float* qs_raw  = (const float*)d_in[2];
  const float* length  = (const float*)d_in[3];
  const float* slope   = (const float*)d_in[4];
  const float* tw      = (const float*)d_in[5];
  const float* ss      = (const float*)d_in[6];
  const float* xs      = (const float*)d_in[7];
  float* out = (float*)d_out;
  float* S1 = (float*)d_ws;                  // 336 x 2048 level-5 series
  float* S2 = S1 + 336 * W1;                 // 336 x 32 level-11 series
  float* D1 = S2 + 336 * W2;                 // 2048-word dump (A dummies/out-of-range)
  float* D2 = D1 + W1;                       // 64-word dump (B: +r, C: +32)
  const int nsent = 336 * W1 + 336 * W2;     // sentinel-init the streams only
  kinit<<<128, 256, 0, stream>>>((unsigned*)d_ws, nsent);
  fused<<<256, 576, 0, stream>>>(q_prime, n_raw, qs_raw, length, slope, tw, ss, xs,
                                 S1, S2, D1, D2, out);
}